// Round 1
// baseline (531.718 us; speedup 1.0000x reference)
//
#include <hip/hip_runtime.h>

#define NQ 11
#define NGD 300
#define NS 10

// Per-pixel independent GD fit: x=(A,Bp,R1), model s_q = A - Bp*exp(-tau_q*R1),
// loss = 0.5*mean_q (s_q - b_q)^2 per pixel (sum over pixels is irrelevant to per-pixel grad).
// grad: gA = mean_q r_q ; gBp = -mean_q r_q*e_q ; gR1 = Bp * mean_q r_q*tau_q*e_q.
// Denoiser in reference is dead code (Dx overwritten by clip(x) == x), lm unused.

__global__ __launch_bounds__(256) void dop_fit_kernel(
    const float* __restrict__ b,    // [P][NQ]
    const float* __restrict__ tau,  // [NQ]  (tau[0] row of (1,NQ))
    const float* __restrict__ mu,   // [NS]
    float* __restrict__ out,        // [2+NS][P][3]
    int P)
{
    const int p = blockIdx.x * blockDim.x + threadIdx.x;
    if (p >= P) return;

    float bq[NQ], tq[NQ], nt[NQ];
#pragma unroll
    for (int q = 0; q < NQ; ++q) {
        bq[q] = b[(size_t)p * NQ + q];
        tq[q] = tau[q];          // uniform address -> scalar loads
        nt[q] = -tq[q];
    }

    // A = max_q |b_q|
    float A = 0.0f;
#pragma unroll
    for (int q = 0; q < NQ; ++q) A = fmaxf(A, fabsf(bq[q]));

    // x0 = clip([A, 2A, 1], 0, [3,6,50]); A>=0 so lower clip is free
    float xA = fminf(A, 3.0f);
    float xB = fminf(2.0f * A, 6.0f);
    float xR = 1.0f;

    const size_t stride = (size_t)P * 3u;
    size_t o = (size_t)p * 3u;
    out[o + 0] = xA; out[o + 1] = xB; out[o + 2] = xR;

    const float inv11 = 1.0f / 11.0f;

    // ---- 300 GD steps, step size 2.0 ----
    for (int it = 0; it < NGD; ++it) {
        float sA = 0.0f, sE = 0.0f, sTE = 0.0f;
#pragma unroll
        for (int q = 0; q < NQ; ++q) {
            float e  = expf(nt[q] * xR);           // accurate ocml exp (baseline)
            float r  = fmaf(-xB, e, xA) - bq[q];   // s_q - b_q
            sA += r;
            float re = r * e;
            sE += re;
            sTE = fmaf(re, tq[q], sTE);
        }
        float gA = sA * inv11;
        float gB = -(sE * inv11);
        float gR = (xB * inv11) * sTE;
        // x - 2*g : fmaf(-2,g,x) is exact-equal to x - (2*g) since 2*g is exact
        xA = fminf(fmaxf(fmaf(-2.0f, gA, xA), 0.0f), 3.0f);
        xB = fminf(fmaxf(fmaf(-2.0f, gB, xB), 0.0f), 6.0f);
        xR = fminf(fmaxf(fmaf(-2.0f, gR, xR), 0.0f), 50.0f);
    }
    o += stride;
    out[o + 0] = xA; out[o + 1] = xB; out[o + 2] = xR;

    // ---- NS PnP steps (denoiser term is exactly zero; d = grad only) ----
    for (int i = 0; i < NS; ++i) {
        const float m = mu[i];
        float sA = 0.0f, sE = 0.0f, sTE = 0.0f;
#pragma unroll
        for (int q = 0; q < NQ; ++q) {
            float e  = expf(nt[q] * xR);
            float r  = fmaf(-xB, e, xA) - bq[q];
            sA += r;
            float re = r * e;
            sE += re;
            sTE = fmaf(re, tq[q], sTE);
        }
        float gA = sA * inv11;
        float gB = -(sE * inv11);
        float gR = (xB * inv11) * sTE;
        xA = fminf(fmaxf(fmaf(-m, gA, xA), 0.0f), 3.0f);
        xB = fminf(fmaxf(fmaf(-m, gB, xB), 0.0f), 6.0f);
        xR = fminf(fmaxf(fmaf(-m, gR, xR), 0.0f), 50.0f);
        o += stride;
        out[o + 0] = xA; out[o + 1] = xB; out[o + 2] = xR;
    }
}

extern "C" void kernel_launch(void* const* d_in, const int* in_sizes, int n_in,
                              void* d_out, int out_size, void* d_ws, size_t ws_size,
                              hipStream_t stream) {
    const float* b   = (const float*)d_in[0];  // (8,192,192,11)
    const float* tau = (const float*)d_in[1];  // (1,11)
    const float* mu  = (const float*)d_in[2];  // (10,)
    // d_in[3] (lm) and d_in[4..9] (denoiser weights) are numerically dead.
    float* out = (float*)d_out;                // (12, 8, 192, 192, 3) f32

    const int P = in_sizes[0] / NQ;            // 294912 pixels
    const int block = 256;
    const int grid = (P + block - 1) / block;
    dop_fit_kernel<<<grid, block, 0, stream>>>(b, tau, mu, out, P);
}

// Round 2
// 245.749 us; speedup vs baseline: 2.1637x; 2.1637x over previous
//
#include <hip/hip_runtime.h>

#define NQ 11
#define NGD 300
#define NS 10

// Per-pixel independent GD fit: x=(A,Bp,R1), model s_q = A - Bp*exp(-tau_q*R1).
// Denoiser in reference is dead code (Dx overwritten by clip(x)==x); NaN scrub dead
// (all quantities bounded). Pure VALU-bound: the lever is instruction count.
// R1->R2 change: v_exp_f32 fast exp2 (2 ops vs ~13 for ocml expf), fmed3 clamps,
// fused mean*step FMAs, 64-thread blocks for load balance.

#if __has_builtin(__builtin_amdgcn_exp2f)
__device__ __forceinline__ float fexp2(float x) { return __builtin_amdgcn_exp2f(x); }
#else
__device__ __forceinline__ float fexp2(float x) {
    float r; asm("v_exp_f32 %0, %1" : "=v"(r) : "v"(x)); return r;
}
#endif

#if __has_builtin(__builtin_amdgcn_fmed3f)
__device__ __forceinline__ float clampm(float x, float lo, float hi) {
    return __builtin_amdgcn_fmed3f(x, lo, hi);
}
#else
__device__ __forceinline__ float clampm(float x, float lo, float hi) {
    return fminf(fmaxf(x, lo), hi);
}
#endif

__global__ __launch_bounds__(64) void dop_fit_kernel(
    const float* __restrict__ b,    // [P][NQ]
    const float* __restrict__ tau,  // [NQ]
    const float* __restrict__ mu,   // [NS]
    float* __restrict__ out,        // [2+NS][P][3]
    int P)
{
    const int p = blockIdx.x * blockDim.x + threadIdx.x;
    if (p >= P) return;

    const float LOG2E = 1.44269504088896340736f;
    float bq[NQ], tq[NQ], cq[NQ];
#pragma unroll
    for (int q = 0; q < NQ; ++q) {
        bq[q] = b[(size_t)p * NQ + q];
        tq[q] = tau[q];              // uniform -> s_load
        cq[q] = -tq[q] * LOG2E;      // exp(-t*R) = exp2(cq*R)
    }

    float A = 0.0f;
#pragma unroll
    for (int q = 0; q < NQ; ++q) A = fmaxf(A, fabsf(bq[q]));

    float xA = fminf(A, 3.0f);
    float xB = fminf(2.0f * A, 6.0f);
    float xR = 1.0f;

    const size_t stride = (size_t)P * 3u;
    size_t o = (size_t)p * 3u;
    out[o + 0] = xA; out[o + 1] = xB; out[o + 2] = xR;

    const float inv11 = 1.0f / 11.0f;

    // one step with effective rate a = stepsize/11; gradients use OLD xB for R-update
    auto step = [&](float a) {
        float sA = 0.0f, sE = 0.0f, sTE = 0.0f;
#pragma unroll
        for (int q = 0; q < NQ; ++q) {
            float e  = fexp2(cq[q] * xR);            // v_mul + v_exp
            float r  = fmaf(-xB, e, xA - bq[q]);     // s_q - b_q
            sA += r;
            float re = r * e;
            sE += re;
            sTE = fmaf(re, tq[q], sTE);
        }
        float mR = a * xB;                            // old xB
        xA = clampm(fmaf(-a, sA, xA), 0.0f, 3.0f);    // gA = sA/11
        xB = clampm(fmaf( a, sE, xB), 0.0f, 6.0f);    // gB = -sE/11
        xR = clampm(fmaf(-mR, sTE, xR), 0.0f, 50.0f); // gR = xB*sTE/11
    };

    const float aGD = 2.0f * inv11;
    for (int it = 0; it < NGD; ++it) step(aGD);

    o += stride;
    out[o + 0] = xA; out[o + 1] = xB; out[o + 2] = xR;

    for (int i = 0; i < NS; ++i) {
        step(mu[i] * inv11);
        o += stride;
        out[o + 0] = xA; out[o + 1] = xB; out[o + 2] = xR;
    }
}

extern "C" void kernel_launch(void* const* d_in, const int* in_sizes, int n_in,
                              void* d_out, int out_size, void* d_ws, size_t ws_size,
                              hipStream_t stream) {
    const float* b   = (const float*)d_in[0];  // (8,192,192,11)
    const float* tau = (const float*)d_in[1];  // (1,11)
    const float* mu  = (const float*)d_in[2];  // (10,)
    float* out = (float*)d_out;                // (12, 8, 192, 192, 3) f32

    const int P = in_sizes[0] / NQ;            // 294912
    const int block = 64;
    const int grid = (P + block - 1) / block;
    dop_fit_kernel<<<grid, block, 0, stream>>>(b, tau, mu, out, P);
}

// Round 3
// 220.308 us; speedup vs baseline: 2.4135x; 1.1155x over previous
//
#include <hip/hip_runtime.h>

#define NQ 11
#define NGD 300
#define NS 10

typedef float v2f __attribute__((ext_vector_type(2)));

// Per-pixel independent GD fit: x=(A,Bp,R1), model s_q = A - Bp*exp(-tau_q*R1).
// Denoiser in reference is dead code (Dx overwritten by clip(x)==x); NaN scrub dead.
// R2->R3: (1) packed fp32 (v_pk_*) over q-pairs: 5 float2 pairs + 1 scalar q,
// (2) exact period-2 early exit on the 300-step GD loop (step-pair granularity;
// bitwise x_{n+2}==x_n for all 64 lanes => all later iterates cycle, remaining
// step count is even => x_300 == current x, exactly).

__device__ __forceinline__ float fexp2(float x) {
#if __has_builtin(__builtin_amdgcn_exp2f)
    return __builtin_amdgcn_exp2f(x);
#else
    float r; asm("v_exp_f32 %0, %1" : "=v"(r) : "v"(x)); return r;
#endif
}
__device__ __forceinline__ float clampm(float x, float lo, float hi) {
#if __has_builtin(__builtin_amdgcn_fmed3f)
    return __builtin_amdgcn_fmed3f(x, lo, hi);
#else
    return fminf(fmaxf(x, lo), hi);
#endif
}

__global__ __launch_bounds__(64) void dop_fit_kernel(
    const float* __restrict__ b,    // [P][NQ]
    const float* __restrict__ tau,  // [NQ]
    const float* __restrict__ mu,   // [NS]
    float* __restrict__ out,        // [2+NS][P][3]
    int P)
{
    const int p = blockIdx.x * blockDim.x + threadIdx.x;
    if (p >= P) return;

    const float LOG2E = 1.44269504088896340736f;

    float bq[NQ];
#pragma unroll
    for (int q = 0; q < NQ; ++q) bq[q] = b[(size_t)p * NQ + q];

    v2f tq2[5], ct2[5], nb2[5];
#pragma unroll
    for (int j = 0; j < 5; ++j) {
        float t0 = tau[2 * j], t1 = tau[2 * j + 1];   // uniform -> s_load
        tq2[j] = (v2f){t0, t1};
        ct2[j] = (v2f){-t0 * LOG2E, -t1 * LOG2E};
        nb2[j] = (v2f){-bq[2 * j], -bq[2 * j + 1]};
    }
    const float t10 = tau[10];
    const float ct10 = -t10 * LOG2E;
    const float nb10 = -bq[10];

    float A = 0.0f;
#pragma unroll
    for (int q = 0; q < NQ; ++q) A = fmaxf(A, fabsf(bq[q]));

    float xA = fminf(A, 3.0f);
    float xB = fminf(2.0f * A, 6.0f);
    float xR = 1.0f;

    const size_t stride = (size_t)P * 3u;
    size_t o = (size_t)p * 3u;
    out[o + 0] = xA; out[o + 1] = xB; out[o + 2] = xR;

    const float inv11 = 1.0f / 11.0f;

    // one GD/PnP step with effective rate a = stepsize/11
    auto step = [&](float a) {
        v2f sA2 = (v2f){0.f, 0.f}, sE2 = (v2f){0.f, 0.f}, sT2 = (v2f){0.f, 0.f};
        const v2f xA2  = (v2f){xA, xA};
        const v2f nxB2 = (v2f){-xB, -xB};
#pragma unroll
        for (int j = 0; j < 5; ++j) {
            v2f m2 = ct2[j] * xR;                                   // pk_mul (xR splat)
            v2f e2; e2.x = fexp2(m2.x); e2.y = fexp2(m2.y);         // 2x v_exp_f32
            v2f r2 = __builtin_elementwise_fma(nxB2, e2, xA2) + nb2[j]; // pk_fma + pk_add
            sA2 += r2;                                              // pk_add
            v2f re2 = r2 * e2;                                      // pk_mul
            sE2 += re2;                                             // pk_add
            sT2 = __builtin_elementwise_fma(re2, tq2[j], sT2);      // pk_fma
        }
        // leftover q = 10 (scalar)
        float e  = fexp2(ct10 * xR);
        float r  = fmaf(-xB, e, xA) + nb10;
        float re = r * e;
        float sA = (sA2.x + sA2.y) + r;
        float sE = (sE2.x + sE2.y) + re;
        float sT = (sT2.x + sT2.y) + re * t10;
        float mR = a * xB;                                          // old xB
        xA = clampm(fmaf(-a,  sA, xA), 0.0f, 3.0f);
        xB = clampm(fmaf( a,  sE, xB), 0.0f, 6.0f);
        xR = clampm(fmaf(-mR, sT, xR), 0.0f, 50.0f);
    };

    const float aGD = 2.0f * inv11;
    // ---- 300 GD steps in pairs, exact period-2 early exit ----
    for (int n = 0; n < NGD; n += 2) {
        const float pA = xA, pB = xB, pR = xR;
        step(aGD);
        step(aGD);
        if (__builtin_expect(__all((xA == pA) & (xB == pB) & (xR == pR)), 0))
            break;  // exact cycle; remaining steps even => x_300 == current x
    }

    o += stride;
    out[o + 0] = xA; out[o + 1] = xB; out[o + 2] = xR;

    // ---- NS PnP steps (denoiser term exactly zero) ----
    for (int i = 0; i < NS; ++i) {
        step(mu[i] * inv11);
        o += stride;
        out[o + 0] = xA; out[o + 1] = xB; out[o + 2] = xR;
    }
}

extern "C" void kernel_launch(void* const* d_in, const int* in_sizes, int n_in,
                              void* d_out, int out_size, void* d_ws, size_t ws_size,
                              hipStream_t stream) {
    const float* b   = (const float*)d_in[0];  // (8,192,192,11)
    const float* tau = (const float*)d_in[1];  // (1,11)
    const float* mu  = (const float*)d_in[2];  // (10,)
    float* out = (float*)d_out;                // (12, 8, 192, 192, 3) f32

    const int P = in_sizes[0] / NQ;            // 294912
    const int block = 64;
    const int grid = (P + block - 1) / block;
    dop_fit_kernel<<<grid, block, 0, stream>>>(b, tau, mu, out, P);
}